// Round 3
// baseline (382.663 us; speedup 1.0000x reference)
//
#include <hip/hip_runtime.h>
#include <math.h>

#define ALPHA   0.8f
#define BSZ     512
#define DDIM    1024
#define NPOS    16
#define NNEG    128
#define NCHUNK  9      // chunk 0 = the 16 positives; chunks 1..8 = 16 negatives each

// Workspace layout (floats):
//   [0,        BSZ)            diag[b]
//   [BSZ,      2*BSZ)          inv_src_norm[b]
//   [2*BSZ,    2*BSZ+BSZ*9)    chunk_sums[b][chunk]

__device__ __forceinline__ float wave_red_sum(float v) {
    #pragma unroll
    for (int off = 32; off > 0; off >>= 1) v += __shfl_xor(v, off, 64);
    return v;
}

// --- Kernel 1: per-row norms of src/tgt + diag = cos(src,tgt) -----------------
__global__ __launch_bounds__(256)
void k1_norms(const float* __restrict__ src, const float* __restrict__ tgt,
              float* __restrict__ diag, float* __restrict__ inv_ns) {
    const int b = blockIdx.x;
    const int t = threadIdx.x;
    const float4 s  = ((const float4*)(src + (size_t)b * DDIM))[t];
    const float4 tg = ((const float4*)(tgt + (size_t)b * DDIM))[t];
    float ss = s.x*s.x + s.y*s.y + s.z*s.z + s.w*s.w;
    float tt = tg.x*tg.x + tg.y*tg.y + tg.z*tg.z + tg.w*tg.w;
    float st = s.x*tg.x + s.y*tg.y + s.z*tg.z + s.w*tg.w;

    ss = wave_red_sum(ss); tt = wave_red_sum(tt); st = wave_red_sum(st);

    __shared__ float red[3][4];
    const int wave = t >> 6, lane = t & 63;
    if (lane == 0) { red[0][wave] = ss; red[1][wave] = tt; red[2][wave] = st; }
    __syncthreads();
    if (t == 0) {
        float S = red[0][0] + red[0][1] + red[0][2] + red[0][3];
        float T = red[1][0] + red[1][1] + red[1][2] + red[1][3];
        float X = red[2][0] + red[2][1] + red[2][2] + red[2][3];
        float ns = fmaxf(sqrtf(S), 1e-12f);
        float nt = fmaxf(sqrtf(T), 1e-12f);
        diag[b]   = X / (ns * nt);
        inv_ns[b] = 1.0f / ns;
    }
}

// --- Kernel 2: streaming pass over passages; exp-sum per (b, chunk) ----------
// grid = (NCHUNK, BSZ), block = 256 (4 waves). Each wave owns 4 passage rows.
__global__ __launch_bounds__(256)
void k2_passages(const float* __restrict__ src,
                 const float* __restrict__ rel,
                 const float* __restrict__ irr,
                 const float* __restrict__ inv_ns,
                 float* __restrict__ chunk_sums) {
    const int chunk = blockIdx.x;   // 0..8
    const int b     = blockIdx.y;
    const int t     = threadIdx.x;

    __shared__ float srcn[DDIM];
    const float inv = inv_ns[b];
    float4 s = ((const float4*)(src + (size_t)b * DDIM))[t];
    s.x *= inv; s.y *= inv; s.z *= inv; s.w *= inv;
    ((float4*)srcn)[t] = s;
    __syncthreads();

    const int wave = t >> 6, lane = t & 63;

    const float* base = (chunk == 0)
        ? (rel + (size_t)b * NPOS * DDIM)
        : (irr + (size_t)b * NNEG * DDIM + (size_t)(chunk - 1) * 16 * DDIM);

    float dot[4] = {0.f, 0.f, 0.f, 0.f};
    float ssq[4] = {0.f, 0.f, 0.f, 0.f};

    #pragma unroll
    for (int c = 0; c < 4; ++c) {
        const float4 sv = ((const float4*)srcn)[c * 64 + lane];
        #pragma unroll
        for (int j = 0; j < 4; ++j) {
            const float4* row = (const float4*)(base + (size_t)(wave * 4 + j) * DDIM);
            const float4 x = row[c * 64 + lane];
            dot[j] += x.x*sv.x + x.y*sv.y + x.z*sv.z + x.w*sv.w;
            ssq[j] += x.x*x.x + x.y*x.y + x.z*x.z + x.w*x.w;
        }
    }

    float acc = 0.f;
    #pragma unroll
    for (int j = 0; j < 4; ++j) {
        const float dj = wave_red_sum(dot[j]);
        const float sj = wave_red_sum(ssq[j]);
        const float sim = dj / fmaxf(sqrtf(sj), 1e-12f);
        acc += expf(sim);
    }

    __shared__ float wsum[4];
    if (lane == 0) wsum[wave] = acc;
    __syncthreads();
    if (t == 0)
        chunk_sums[(size_t)b * NCHUNK + chunk] = wsum[0] + wsum[1] + wsum[2] + wsum[3];
}

// --- Kernel 3: per-b loss term + mean ----------------------------------------
__global__ __launch_bounds__(512)
void k3_final(const float* __restrict__ diag,
              const float* __restrict__ chunk_sums,
              float* __restrict__ out) {
    const int b = threadIdx.x;      // 0..511
    float pos = 1.0f + chunk_sums[(size_t)b * NCHUNK + 0];
    float neg = 0.f;
    #pragma unroll
    for (int c = 1; c < NCHUNK; ++c) neg += chunk_sums[(size_t)b * NCHUNK + c];

    const float loss_pos = logf(pos);
    const float loss_neg = logf(pos + neg);
    float term = -(ALPHA * diag[b] + (1.0f - ALPHA) * (loss_pos - loss_neg));

    float v = wave_red_sum(term);
    __shared__ float wsum[8];
    const int wave = b >> 6, lane = b & 63;
    if (lane == 0) wsum[wave] = v;
    __syncthreads();
    if (b == 0) {
        float ssum = 0.f;
        #pragma unroll
        for (int i = 0; i < 8; ++i) ssum += wsum[i];
        out[0] = ssum / (float)BSZ;
    }
}

extern "C" void kernel_launch(void* const* d_in, const int* in_sizes, int n_in,
                              void* d_out, int out_size, void* d_ws, size_t ws_size,
                              hipStream_t stream) {
    const float* src = (const float*)d_in[0];   // embeddings_src      [B, D]
    const float* tgt = (const float*)d_in[1];   // embeddings_target   [B, D]
    const float* rel = (const float*)d_in[2];   // relevant_passage    [B, P, D]
    const float* irr = (const float*)d_in[3];   // irrelevant_passage  [B, N, D]
    float* out = (float*)d_out;

    float* ws        = (float*)d_ws;
    float* diag      = ws;
    float* inv_ns    = ws + BSZ;
    float* chunk_sums= ws + 2 * BSZ;

    k1_norms<<<BSZ, 256, 0, stream>>>(src, tgt, diag, inv_ns);
    dim3 g2(NCHUNK, BSZ);
    k2_passages<<<g2, 256, 0, stream>>>(src, rel, irr, inv_ns, chunk_sums);
    k3_final<<<1, 512, 0, stream>>>(diag, chunk_sums, out);
}

// Round 4
// 377.128 us; speedup vs baseline: 1.0147x; 1.0147x over previous
//
#include <hip/hip_runtime.h>
#include <math.h>

#define ALPHA   0.8f
#define BSZ     512
#define DDIM    1024
#define NPOS    16
#define NNEG    128
#define NCHUNK  9      // chunk 0 = 16 positives; chunks 1..8 = 16 negatives each
// kA grid.x = 10: chunks 0..8 stream passages; chunk 9 computes diag[b].

// Workspace layout (floats):
//   [0,     BSZ)             diag[b]
//   [BSZ,   BSZ + BSZ*9)     chunk_sums[b][chunk]

__device__ __forceinline__ float wave_red_sum(float v) {
    #pragma unroll
    for (int off = 32; off > 0; off >>= 1) v += __shfl_xor(v, off, 64);
    return v;
}

// --- Kernel A: fused diag + streaming exp-sum per (b, chunk) ------------------
// grid = (10, BSZ), block = 256 (4 waves). Chunks 0..8: each wave owns 4
// passage rows; src row staged RAW in LDS; ssq(src) computed by each wave
// during the c-loop (it traverses the full row), so no separate norm kernel
// and no inter-kernel dependency. Chunk 9: diag = cos(src, tgt).
__global__ __launch_bounds__(256)
void kA_fused(const float* __restrict__ src,
              const float* __restrict__ tgt,
              const float* __restrict__ rel,
              const float* __restrict__ irr,
              float* __restrict__ diag,
              float* __restrict__ chunk_sums) {
    const int chunk = blockIdx.x;   // 0..9
    const int b     = blockIdx.y;
    const int t     = threadIdx.x;
    const int wave  = t >> 6, lane = t & 63;

    if (chunk == 9) {
        // diag chunk: 256 threads cover the 1024-d row as float4 each.
        const float4 s = ((const float4*)(src + (size_t)b * DDIM))[t];
        const float4 g = ((const float4*)(tgt + (size_t)b * DDIM))[t];
        float ss = s.x*s.x + s.y*s.y + s.z*s.z + s.w*s.w;
        float tt = g.x*g.x + g.y*g.y + g.z*g.z + g.w*g.w;
        float st = s.x*g.x + s.y*g.y + s.z*g.z + s.w*g.w;
        ss = wave_red_sum(ss); tt = wave_red_sum(tt); st = wave_red_sum(st);
        __shared__ float red[3][4];
        if (lane == 0) { red[0][wave] = ss; red[1][wave] = tt; red[2][wave] = st; }
        __syncthreads();
        if (t == 0) {
            float S = red[0][0] + red[0][1] + red[0][2] + red[0][3];
            float T = red[1][0] + red[1][1] + red[1][2] + red[1][3];
            float X = red[2][0] + red[2][1] + red[2][2] + red[2][3];
            diag[b] = X / (fmaxf(sqrtf(S), 1e-12f) * fmaxf(sqrtf(T), 1e-12f));
        }
        return;
    }

    __shared__ float srcr[DDIM];    // RAW src row
    ((float4*)srcr)[t] = ((const float4*)(src + (size_t)b * DDIM))[t];
    __syncthreads();

    const float* base = (chunk == 0)
        ? (rel + (size_t)b * NPOS * DDIM)
        : (irr + (size_t)b * NNEG * DDIM + (size_t)(chunk - 1) * 16 * DDIM);

    float dot[4] = {0.f, 0.f, 0.f, 0.f};
    float ssq[4] = {0.f, 0.f, 0.f, 0.f};
    float ssqs   = 0.f;             // ssq of src row (each wave covers full row)

    #pragma unroll
    for (int c = 0; c < 4; ++c) {
        const float4 sv = ((const float4*)srcr)[c * 64 + lane];
        ssqs += sv.x*sv.x + sv.y*sv.y + sv.z*sv.z + sv.w*sv.w;
        #pragma unroll
        for (int j = 0; j < 4; ++j) {
            const float4* row = (const float4*)(base + (size_t)(wave * 4 + j) * DDIM);
            const float4 x = row[c * 64 + lane];
            dot[j] += x.x*sv.x + x.y*sv.y + x.z*sv.z + x.w*sv.w;
            ssq[j] += x.x*x.x + x.y*x.y + x.z*x.z + x.w*x.w;
        }
    }

    ssqs = wave_red_sum(ssqs);
    const float inv_ns = 1.0f / fmaxf(sqrtf(ssqs), 1e-12f);

    float acc = 0.f;
    #pragma unroll
    for (int j = 0; j < 4; ++j) {
        const float dj = wave_red_sum(dot[j]);
        const float sj = wave_red_sum(ssq[j]);
        const float sim = dj * inv_ns / fmaxf(sqrtf(sj), 1e-12f);
        acc += expf(sim);
    }

    __shared__ float wsum[4];
    if (lane == 0) wsum[wave] = acc;
    __syncthreads();
    if (t == 0)
        chunk_sums[(size_t)b * NCHUNK + chunk] = wsum[0] + wsum[1] + wsum[2] + wsum[3];
}

// --- Kernel B: per-b loss term + mean ----------------------------------------
__global__ __launch_bounds__(512)
void kB_final(const float* __restrict__ diag,
              const float* __restrict__ chunk_sums,
              float* __restrict__ out) {
    const int b = threadIdx.x;      // 0..511
    float pos = 1.0f + chunk_sums[(size_t)b * NCHUNK + 0];
    float neg = 0.f;
    #pragma unroll
    for (int c = 1; c < NCHUNK; ++c) neg += chunk_sums[(size_t)b * NCHUNK + c];

    const float loss_pos = logf(pos);
    const float loss_neg = logf(pos + neg);
    float term = -(ALPHA * diag[b] + (1.0f - ALPHA) * (loss_pos - loss_neg));

    float v = wave_red_sum(term);
    __shared__ float wsum[8];
    const int wave = b >> 6, lane = b & 63;
    if (lane == 0) wsum[wave] = v;
    __syncthreads();
    if (b == 0) {
        float ssum = 0.f;
        #pragma unroll
        for (int i = 0; i < 8; ++i) ssum += wsum[i];
        out[0] = ssum / (float)BSZ;
    }
}

extern "C" void kernel_launch(void* const* d_in, const int* in_sizes, int n_in,
                              void* d_out, int out_size, void* d_ws, size_t ws_size,
                              hipStream_t stream) {
    const float* src = (const float*)d_in[0];   // embeddings_src      [B, D]
    const float* tgt = (const float*)d_in[1];   // embeddings_target   [B, D]
    const float* rel = (const float*)d_in[2];   // relevant_passage    [B, P, D]
    const float* irr = (const float*)d_in[3];   // irrelevant_passage  [B, N, D]
    float* out = (float*)d_out;

    float* ws         = (float*)d_ws;
    float* diag       = ws;
    float* chunk_sums = ws + BSZ;

    dim3 gA(NCHUNK + 1, BSZ);
    kA_fused<<<gA, 256, 0, stream>>>(src, tgt, rel, irr, diag, chunk_sums);
    kB_final<<<1, 512, 0, stream>>>(diag, chunk_sums, out);
}